// Round 2
// baseline (1014.856 us; speedup 1.0000x reference)
//
#include <hip/hip_runtime.h>
#include <hip/hip_bf16.h>

typedef __bf16 b8v __attribute__((ext_vector_type(8)));
typedef float  f4v __attribute__((ext_vector_type(4)));

#define AS3(p)  ((__attribute__((address_space(3))) void*)(p))
#define AS1C(p) ((const __attribute__((address_space(1))) void*)(p))

// ============================================================================
// GEMM: C[M,N] = A[M,K] @ Bt[N,K]^T   (A,Bt bf16 row-major K-contig, fp32 acc)
// 128x128 tile, BK=32, 256 threads (2x2 waves of 64x64), mfma_f32_16x16x32_bf16
// EPI: 0 = none, 1 = relu, 2 = bias+gelu.  OBF: 1 = bf16 out, 0 = fp32 out.
// ============================================================================
template<int EPI, int OBF>
__global__ __launch_bounds__(256) void gemm_bt(
    const __hip_bfloat16* __restrict__ A,  long long sA,
    const __hip_bfloat16* __restrict__ Bt, long long sB,
    void* __restrict__ Cv, long long sC,
    const float* __restrict__ bias, int N, int K)
{
  const int bz = blockIdx.z;
  A  += (long long)bz * sA;
  Bt += (long long)bz * sB;

  __shared__ __hip_bfloat16 As[128 * 32];
  __shared__ __hip_bfloat16 Bs[128 * 32];

  const int tid  = threadIdx.x;
  const int lane = tid & 63;
  const int wave = tid >> 6;

  const long long m0 = (long long)blockIdx.x * 128;
  const long long n0 = (long long)blockIdx.y * 128;

  // staging: thread t loads 16B (8 bf16) from tile row (t>>2), k-col (t&3)*8
  const __hip_bfloat16* aSrc = A  + (m0 + (tid >> 2)) * (long long)K + (tid & 3) * 8;
  const __hip_bfloat16* bSrc = Bt + (n0 + (tid >> 2)) * (long long)K + (tid & 3) * 8;

  const int wm = (wave & 1) * 64;
  const int wn = (wave >> 1) * 64;
  const int lm = lane & 15;   // m / n within 16x16 tile
  const int kq = lane >> 4;   // k quad (0..3), each 8 elements

  const int aOff = (wm + lm) * 32 + kq * 8;
  const int bOff = (wn + lm) * 32 + kq * 8;

  f4v acc[4][4];
  const f4v fzero = {0.0f, 0.0f, 0.0f, 0.0f};
#pragma unroll
  for (int i = 0; i < 4; i++)
#pragma unroll
    for (int j = 0; j < 4; j++) acc[i][j] = fzero;

  for (int k0 = 0; k0 < K; k0 += 32) {
    __builtin_amdgcn_global_load_lds(AS1C(aSrc),              AS3(As + tid * 8),        16, 0, 0);
    __builtin_amdgcn_global_load_lds(AS1C(aSrc + 64LL * K),   AS3(As + 2048 + tid * 8), 16, 0, 0);
    __builtin_amdgcn_global_load_lds(AS1C(bSrc),              AS3(Bs + tid * 8),        16, 0, 0);
    __builtin_amdgcn_global_load_lds(AS1C(bSrc + 64LL * K),   AS3(Bs + 2048 + tid * 8), 16, 0, 0);
    __syncthreads();

    b8v af[4], bf[4];
#pragma unroll
    for (int i = 0; i < 4; i++) af[i] = *(const b8v*)(As + aOff + i * 16 * 32);
#pragma unroll
    for (int j = 0; j < 4; j++) bf[j] = *(const b8v*)(Bs + bOff + j * 16 * 32);

#pragma unroll
    for (int i = 0; i < 4; i++)
#pragma unroll
      for (int j = 0; j < 4; j++)
        acc[i][j] = __builtin_amdgcn_mfma_f32_16x16x32_bf16(af[i], bf[j], acc[i][j], 0, 0, 0);

    __syncthreads();
    aSrc += 32; bSrc += 32;
  }

  // epilogue: C/D layout (16x16x32): col = lane&15, row = (lane>>4)*4 + reg
#pragma unroll
  for (int i = 0; i < 4; i++) {
#pragma unroll
    for (int j = 0; j < 4; j++) {
#pragma unroll
      for (int r = 0; r < 4; r++) {
        long long row = m0 + wm + i * 16 + kq * 4 + r;
        long long col = n0 + wn + j * 16 + lm;
        float v = acc[i][j][r];
        if constexpr (EPI == 1) v = fmaxf(v, 0.0f);
        if constexpr (EPI == 2) {
          v += bias[col];
          v = 0.5f * v * (1.0f + erff(v * 0.70710678118654752f));
        }
        long long idx = (long long)bz * sC + row * (long long)N + col;
        if constexpr (OBF) ((__hip_bfloat16*)Cv)[idx] = __float2bfloat16(v);
        else               ((float*)Cv)[idx] = v;
      }
    }
  }
}

// ============================================================================
// adj row-sums -> dinv = 1/sqrt(rowsum).  One wave per row. 16384 rows total.
// ============================================================================
__global__ __launch_bounds__(256) void rowsum_dinv(const float* __restrict__ g,
                                                   float* __restrict__ dinv)
{
  const int wave = threadIdx.x >> 6, lane = threadIdx.x & 63;
  const long long row = (long long)blockIdx.x * 4 + wave;   // [0, 16384)
  const float4* p = (const float4*)(g + row * 1024);
  float s = 0.0f;
#pragma unroll
  for (int k = 0; k < 4; k++) {
    float4 v = p[lane + k * 64];
    s += v.x + v.y + v.z + v.w;
  }
#pragma unroll
  for (int o = 32; o > 0; o >>= 1) s += __shfl_down(s, o);
  if (lane == 0) dinv[row] = 1.0f / sqrtf(s);
}

// ============================================================================
// adj_bf16[b][i][j] = graphs[b][graph][i][j] * dinv[i] * dinv[j]  (one graph)
// ============================================================================
__global__ __launch_bounds__(256) void scale_adj(const float* __restrict__ g,
                                                 const float* __restrict__ dinv,
                                                 __hip_bfloat16* __restrict__ out,
                                                 int graph)
{
  const long long t = (long long)blockIdx.x * 256 + threadIdx.x; // quad index
  const long long e = t * 4;            // within-graph element, [0, 8*2^20)
  const int b = (int)(e >> 20);
  const int i = (int)((e >> 10) & 1023);
  const int j = (int)(e & 1023);
  const int m = b * 2 + graph;          // dinv matrix index
  const float4 v  = *(const float4*)(g + ((long long)m << 20) + (long long)i * 1024 + j);
  const float  di = dinv[m * 1024 + i];
  const float4 dj = *(const float4*)(dinv + m * 1024 + j);
  union { __hip_bfloat16 h[4]; unsigned long long u; } r;
  r.h[0] = __float2bfloat16(v.x * di * dj.x);
  r.h[1] = __float2bfloat16(v.y * di * dj.y);
  r.h[2] = __float2bfloat16(v.z * di * dj.z);
  r.h[3] = __float2bfloat16(v.w * di * dj.w);
  *(unsigned long long*)(out + ((long long)b << 20) + (long long)i * 1024 + j) = r.u;
}

// ============================================================================
// transpose + convert to bf16: out[C,R] = in[R,C], batched via grid.z
// ============================================================================
template<typename TIN>
__global__ void transpose_conv(const TIN* __restrict__ in, __hip_bfloat16* __restrict__ out,
                               int R, int C, long long sIn, long long sOut)
{
  __shared__ __hip_bfloat16 tile[32][33];
  in  += (long long)blockIdx.z * sIn;
  out += (long long)blockIdx.z * sOut;
  const int c0 = blockIdx.x * 32, r0 = blockIdx.y * 32;
  const int tx = threadIdx.x, ty = threadIdx.y;
#pragma unroll
  for (int i = 0; i < 32; i += 8)
    tile[ty + i][tx] = __float2bfloat16((float)in[(long long)(r0 + ty + i) * C + c0 + tx]);
  __syncthreads();
#pragma unroll
  for (int i = 0; i < 32; i += 8)
    out[(long long)(c0 + ty + i) * R + r0 + tx] = tile[tx][ty + i];
}

// ============================================================================
// residual + LayerNorm: y = LN(nodes + V + col_b) -> bf16 slice of Gcat
// one block (256 thr) per row of 768.  V is bf16.
// ============================================================================
__global__ __launch_bounds__(256) void ln_residual(
    const float* __restrict__ nodes, const __hip_bfloat16* __restrict__ V,
    const float* __restrict__ colb,  const float* __restrict__ lng,
    const float* __restrict__ lnb,
    __hip_bfloat16* __restrict__ gcat, int catOff)
{
  const long long row = blockIdx.x;
  const int t = threadIdx.x;
  const long long base = row * 768;
  float x[3]; float s = 0.0f, ss = 0.0f;
#pragma unroll
  for (int i = 0; i < 3; i++) {
    const int c = t + i * 256;
    const float v = nodes[base + c] + __bfloat162float(V[base + c]) + colb[c];
    x[i] = v; s += v; ss += v * v;
  }
  __shared__ float red[8];
#pragma unroll
  for (int o = 32; o > 0; o >>= 1) { s += __shfl_down(s, o); ss += __shfl_down(ss, o); }
  const int wave = t >> 6, lane = t & 63;
  if (lane == 0) { red[wave] = s; red[4 + wave] = ss; }
  __syncthreads();
  if (t == 0) {
    red[0] = red[0] + red[1] + red[2] + red[3];
    red[4] = red[4] + red[5] + red[6] + red[7];
  }
  __syncthreads();
  const float mu  = red[0] * (1.0f / 768.0f);
  float var = red[4] * (1.0f / 768.0f) - mu * mu;
  var = fmaxf(var, 0.0f);
  const float rs = rsqrtf(var + 1e-12f);
#pragma unroll
  for (int i = 0; i < 3; i++) {
    const int c = t + i * 256;
    const float y = (x[i] - mu) * rs * lng[c] + lnb[c];
    gcat[row * 1536 + catOff + c] = __float2bfloat16(y);
  }
}

// ============================================================================
// WeffT[n][k] (bf16, [768,1536]): folded gate weight
//   k<768 : (Wa+Wc+Wd)[k][n];  k>=768: (Wb+Wc-Wd)[k-768][n]
// ============================================================================
__global__ __launch_bounds__(256) void build_wefft(const float* __restrict__ gw,
                                                   __hip_bfloat16* __restrict__ wt)
{
  const int idx = blockIdx.x * 256 + threadIdx.x;  // 768*1536, exact
  const int n = idx / 1536, k = idx % 1536;
  float v;
  if (k < 768) v = gw[k * 768 + n] + gw[(1536 + k) * 768 + n] + gw[(2304 + k) * 768 + n];
  else {
    const int kk = k - 768;
    v = gw[(768 + kk) * 768 + n] + gw[(1536 + kk) * 768 + n] - gw[(2304 + kk) * 768 + n];
  }
  wt[idx] = __float2bfloat16(v);
}

// ============================================================================
// out = sigmoid(logits + gate_b) * g1 + (1-sigmoid) * g2  (g1,g2 = Gcat halves)
// ============================================================================
__global__ __launch_bounds__(256) void final_gate(
    const float* __restrict__ logits, const float* __restrict__ gb,
    const __hip_bfloat16* __restrict__ gcat, float* __restrict__ out)
{
  const unsigned int t = blockIdx.x * 256u + threadIdx.x;  // quad index, < 1572864
  const unsigned int row = t / 192u;          // 192 quads per row of 768
  const unsigned int col = (t % 192u) * 4u;
  const long long e = (long long)row * 768 + col;
  const float4 L = *(const float4*)(logits + e);
  const float4 B = *(const float4*)(gb + col);
  union { __hip_bfloat16 h[4]; unsigned long long u; } g1, g2;
  g1.u = *(const unsigned long long*)(gcat + (long long)row * 1536 + col);
  g2.u = *(const unsigned long long*)(gcat + (long long)row * 1536 + 768 + col);
  float4 o;
  {
    float a = __bfloat162float(g1.h[0]), b = __bfloat162float(g2.h[0]);
    float s = 1.0f / (1.0f + expf(-(L.x + B.x))); o.x = s * a + (1.0f - s) * b;
  }
  {
    float a = __bfloat162float(g1.h[1]), b = __bfloat162float(g2.h[1]);
    float s = 1.0f / (1.0f + expf(-(L.y + B.y))); o.y = s * a + (1.0f - s) * b;
  }
  {
    float a = __bfloat162float(g1.h[2]), b = __bfloat162float(g2.h[2]);
    float s = 1.0f / (1.0f + expf(-(L.z + B.z))); o.z = s * a + (1.0f - s) * b;
  }
  {
    float a = __bfloat162float(g1.h[3]), b = __bfloat162float(g2.h[3]);
    float s = 1.0f / (1.0f + expf(-(L.w + B.w))); o.w = s * a + (1.0f - s) * b;
  }
  *(float4*)(out + e) = o;
}

// ============================================================================
extern "C" void kernel_launch(void* const* d_in, const int* in_sizes, int n_in,
                              void* d_out, int out_size, void* d_ws, size_t ws_size,
                              hipStream_t stream)
{
  const float* nodes  = (const float*)d_in[0];
  const float* graphs = (const float*)d_in[1];
  const float* gcn_w1[2] = { (const float*)d_in[2], (const float*)d_in[4] };
  const float* gcn_w2[2] = { (const float*)d_in[3], (const float*)d_in[5] };
  const float* exp_w[2]  = { (const float*)d_in[6],  (const float*)d_in[10] };
  const float* exp_b[2]  = { (const float*)d_in[7],  (const float*)d_in[11] };
  const float* col_w[2]  = { (const float*)d_in[8],  (const float*)d_in[12] };
  const float* col_b[2]  = { (const float*)d_in[9],  (const float*)d_in[13] };
  const float* gate_w = (const float*)d_in[14];
  const float* gate_b = (const float*)d_in[15];
  const float* ln_g[2] = { (const float*)d_in[16], (const float*)d_in[18] };
  const float* ln_b[2] = { (const float*)d_in[17], (const float*)d_in[19] };
  float* out = (float*)d_out;

  // ---- workspace carve-up (~145 MiB total; all 256B aligned, heavy reuse) ----
  char* w = (char*)d_ws;
  auto alloc = [&](size_t bytes) { char* p = w; w += (bytes + 255) & ~(size_t)255; return p; };
  float*          dinv  = (float*)alloc(16384ULL * 4);                      // 64 KiB
  __hip_bfloat16* Xt    = (__hip_bfloat16*)alloc(8ULL * 768 * 1024 * 2);    // 12 MiB
  __hip_bfloat16* Gcat  = (__hip_bfloat16*)alloc(8ULL * 1024 * 1536 * 2);   // 24 MiB
  __hip_bfloat16* wefft = (__hip_bfloat16*)alloc(768ULL * 1536 * 2);        // 2.25 MiB
  __hip_bfloat16* adj   = (__hip_bfloat16*)alloc(8ULL * 1024 * 1024 * 2);   // 16 MiB (per-graph)
  __hip_bfloat16* w1T   = (__hip_bfloat16*)alloc(3072ULL * 768 * 2);        // 4.5 MiB
  __hip_bfloat16* w2T   = (__hip_bfloat16*)alloc(768ULL * 3072 * 2);        // 4.5 MiB
  __hip_bfloat16* expT  = (__hip_bfloat16*)alloc(3072ULL * 768 * 2);        // 4.5 MiB
  __hip_bfloat16* colT  = (__hip_bfloat16*)alloc(768ULL * 3072 * 2);        // 4.5 MiB
  __hip_bfloat16* bufA  = (__hip_bfloat16*)alloc(8ULL * 1024 * 768 * 2);    // 12 MiB: AX / T2t / V
  __hip_bfloat16* bufB  = (__hip_bfloat16*)alloc(8ULL * 1024 * 768 * 2);    // 12 MiB: T2 / Gb
  __hip_bfloat16* X1    = (__hip_bfloat16*)alloc(8ULL * 1024 * 3072 * 2);   // 48 MiB: X1 / U / logits(f32)
  float*          logits = (float*)X1;  // 24 MiB fp32 fits in X1 slot (dead by then)

  // ---- one-time prep ----
  rowsum_dinv<<<4096, 256, 0, stream>>>(graphs, dinv);
  // nodes [8][1024,768] -> Xt [8][768,1024]
  transpose_conv<float><<<dim3(24, 32, 8), dim3(32, 8), 0, stream>>>(
      nodes, Xt, 1024, 768, 1024LL * 768, 768LL * 1024);
  build_wefft<<<4608, 256, 0, stream>>>(gate_w, wefft);

  // ---- per-graph pipeline (buffers reused across graphs) ----
  for (int g = 0; g < 2; g++) {
    scale_adj<<<8192, 256, 0, stream>>>(graphs, dinv, adj, g);
    transpose_conv<float><<<dim3(96, 24, 1), dim3(32, 8), 0, stream>>>(
        gcn_w1[g], w1T, 768, 3072, 0, 0);
    transpose_conv<float><<<dim3(24, 96, 1), dim3(32, 8), 0, stream>>>(
        gcn_w2[g], w2T, 3072, 768, 0, 0);
    transpose_conv<float><<<dim3(96, 24, 1), dim3(32, 8), 0, stream>>>(
        exp_w[g], expT, 768, 3072, 0, 0);
    transpose_conv<float><<<dim3(24, 96, 1), dim3(32, 8), 0, stream>>>(
        col_w[g], colT, 3072, 768, 0, 0);

    // AX = adj @ X            [1024,1024]@[1024,768], batched  -> bufA
    gemm_bt<0, 1><<<dim3(8, 6, 8), 256, 0, stream>>>(
        adj, 1024LL * 1024, Xt, 768LL * 1024, bufA, 1024LL * 768, nullptr, 768, 1024);
    // X1 = relu(AX @ W1)      [8192,768]@[768,3072]
    gemm_bt<1, 1><<<dim3(64, 24, 1), 256, 0, stream>>>(
        bufA, 0, w1T, 0, X1, 0, nullptr, 3072, 768);
    // T2 = X1 @ W2            [8192,3072]@[3072,768]  -> bufB
    gemm_bt<0, 1><<<dim3(64, 6, 1), 256, 0, stream>>>(
        X1, 0, w2T, 0, bufB, 0, nullptr, 768, 3072);
    // T2t = transpose(T2) per batch  -> bufA (AX dead)
    transpose_conv<__hip_bfloat16><<<dim3(24, 32, 8), dim3(32, 8), 0, stream>>>(
        bufB, bufA, 1024, 768, 1024LL * 768, 768LL * 1024);
    // G = relu(adj @ T2)      [1024,1024]@[1024,768], batched  -> bufB (T2 dead)
    gemm_bt<1, 1><<<dim3(8, 6, 8), 256, 0, stream>>>(
        adj, 1024LL * 1024, bufA, 768LL * 1024, bufB, 1024LL * 768, nullptr, 768, 1024);
    // U = gelu(G @ expW + exp_b)  [8192,768]@[768,3072]  -> X1 (X1 dead)
    gemm_bt<2, 1><<<dim3(64, 24, 1), 256, 0, stream>>>(
        bufB, 0, expT, 0, X1, 0, exp_b[g], 3072, 768);
    // V = U @ colW            [8192,3072]@[3072,768], bf16 out -> bufA (T2t dead)
    gemm_bt<0, 1><<<dim3(64, 6, 1), 256, 0, stream>>>(
        X1, 0, colT, 0, bufA, 0, nullptr, 768, 3072);
    // LN(nodes + V + col_b) -> Gcat[:, g*768:(g+1)*768] bf16
    ln_residual<<<8192, 256, 0, stream>>>(
        nodes, bufA, col_b[g], ln_g[g], ln_b[g], Gcat, g * 768);
  }

  // logits = Gcat @ WeffT^T   [8192,1536]@[1536,768], fp32 out -> X1 slot
  gemm_bt<0, 0><<<dim3(64, 6, 1), 256, 0, stream>>>(
      Gcat, 0, wefft, 0, logits, 0, nullptr, 768, 1536);
  final_gate<<<6144, 256, 0, stream>>>(logits, gate_b, Gcat, out);
}

// Round 3
// 865.636 us; speedup vs baseline: 1.1724x; 1.1724x over previous
//
#include <hip/hip_runtime.h>
#include <hip/hip_bf16.h>

typedef __bf16 b8v __attribute__((ext_vector_type(8)));
typedef float  f4v __attribute__((ext_vector_type(4)));

#define AS3(p)  ((__attribute__((address_space(3))) void*)(p))
#define AS1C(p) ((const __attribute__((address_space(1))) void*)(p))

// ============================================================================
// GEMM: C[M,N] = A[M,K] @ Bt[N,K]^T   (A,Bt bf16 row-major K-contig, fp32 acc)
// 128x128 tile, BK=32, 256 threads (2x2 waves of 64x64), mfma_f32_16x16x32_bf16
// LDS k-cell XOR swizzle: staging thread t loads global k-cell (t&3)^((t>>4)&3)
// so fragment reads hit each 16B bank-group exactly 2x (free on CDNA4).
// EPI: 0 = none, 1 = relu, 2 = bias+gelu (bias chosen by z&1).
// OBF: 1 = bf16 out, 0 = fp32 out.  bMask: Bt batch index = z & bMask.
// ============================================================================
template<int EPI, int OBF>
__global__ __launch_bounds__(256) void gemm_bt(
    const __hip_bfloat16* __restrict__ A,  long long sA,
    const __hip_bfloat16* __restrict__ Bt, long long sB,
    void* __restrict__ Cv, long long sC,
    const float* __restrict__ bias0, const float* __restrict__ bias1,
    int N, int K, int bMask)
{
  const int bz = blockIdx.z;
  A  += (long long)bz * sA;
  Bt += (long long)(bz & bMask) * sB;
  const float* __restrict__ bias = (bz & 1) ? bias1 : bias0;

  __shared__ __hip_bfloat16 As[128 * 32];
  __shared__ __hip_bfloat16 Bs[128 * 32];

  const int tid  = threadIdx.x;
  const int lane = tid & 63;
  const int wave = tid >> 6;

  const long long m0 = (long long)blockIdx.x * 128;
  const long long n0 = (long long)blockIdx.y * 128;

  // staging: thread t -> tile row r = t>>2, LDS slot c = t&3,
  // global k-cell kc = c ^ ((r>>2)&3)   (swizzle; rows 64..127 same since 16%4==0)
  const int r  = tid >> 2;
  const int kc = (tid & 3) ^ ((r >> 2) & 3);
  const __hip_bfloat16* aSrc = A  + (m0 + r) * (long long)K + kc * 8;
  const __hip_bfloat16* bSrc = Bt + (n0 + r) * (long long)K + kc * 8;

  const int wm = (wave & 1) * 64;
  const int wn = (wave >> 1) * 64;
  const int lm = lane & 15;   // m / n within 16x16 tile
  const int kq = lane >> 4;   // k quad (0..3), each 8 elements

  // read: slot s holds global k-cell s ^ ((row>>2)&3); want kq -> s = kq ^ sw
  const int sw   = (lm >> 2) & 3;   // (wm + lm + 16*i) preserves this for all i
  const int aOff = (wm + lm) * 32 + ((kq ^ sw)) * 8;
  const int bOff = (wn + lm) * 32 + ((kq ^ sw)) * 8;

  f4v acc[4][4];
  const f4v fzero = {0.0f, 0.0f, 0.0f, 0.0f};
#pragma unroll
  for (int i = 0; i < 4; i++)
#pragma unroll
    for (int j = 0; j < 4; j++) acc[i][j] = fzero;

  for (int k0 = 0; k0 < K; k0 += 32) {
    __builtin_amdgcn_global_load_lds(AS1C(aSrc),              AS3(As + tid * 8),        16, 0, 0);
    __builtin_amdgcn_global_load_lds(AS1C(aSrc + 64LL * K),   AS3(As + 2048 + tid * 8), 16, 0, 0);
    __builtin_amdgcn_global_load_lds(AS1C(bSrc),              AS3(Bs + tid * 8),        16, 0, 0);
    __builtin_amdgcn_global_load_lds(AS1C(bSrc + 64LL * K),   AS3(Bs + 2048 + tid * 8), 16, 0, 0);
    __syncthreads();

    b8v af[4], bf[4];
#pragma unroll
    for (int i = 0; i < 4; i++) af[i] = *(const b8v*)(As + aOff + i * 16 * 32);
#pragma unroll
    for (int j = 0; j < 4; j++) bf[j] = *(const b8v*)(Bs + bOff + j * 16 * 32);

#pragma unroll
    for (int i = 0; i < 4; i++)
#pragma unroll
      for (int j = 0; j < 4; j++)
        acc[i][j] = __builtin_amdgcn_mfma_f32_16x16x32_bf16(af[i], bf[j], acc[i][j], 0, 0, 0);

    __syncthreads();
    aSrc += 32; bSrc += 32;
  }

  // epilogue: C/D layout (16x16x32): col = lane&15, row = (lane>>4)*4 + reg
#pragma unroll
  for (int i = 0; i < 4; i++) {
#pragma unroll
    for (int j = 0; j < 4; j++) {
#pragma unroll
      for (int rg = 0; rg < 4; rg++) {
        long long row = m0 + wm + i * 16 + kq * 4 + rg;
        long long col = n0 + wn + j * 16 + lm;
        float v = acc[i][j][rg];
        if constexpr (EPI == 1) v = fmaxf(v, 0.0f);
        if constexpr (EPI == 2) {
          v += bias[col];
          v = 0.5f * v * (1.0f + erff(v * 0.70710678118654752f));
        }
        long long idx = (long long)bz * sC + row * (long long)N + col;
        if constexpr (OBF) ((__hip_bfloat16*)Cv)[idx] = __float2bfloat16(v);
        else               ((float*)Cv)[idx] = v;
      }
    }
  }
}

// ============================================================================
// adj row-sums -> dinv = 1/sqrt(rowsum).  One wave per row. 16384 rows total.
// ============================================================================
__global__ __launch_bounds__(256) void rowsum_dinv(const float* __restrict__ g,
                                                   float* __restrict__ dinv)
{
  const int wave = threadIdx.x >> 6, lane = threadIdx.x & 63;
  const long long row = (long long)blockIdx.x * 4 + wave;   // [0, 16384)
  const float4* p = (const float4*)(g + row * 1024);
  float s = 0.0f;
#pragma unroll
  for (int k = 0; k < 4; k++) {
    float4 v = p[lane + k * 64];
    s += v.x + v.y + v.z + v.w;
  }
#pragma unroll
  for (int o = 32; o > 0; o >>= 1) s += __shfl_down(s, o);
  if (lane == 0) dinv[row] = 1.0f / sqrtf(s);
}

// ============================================================================
// adj_bf16[g][b][i][j] = graphs[b][g][i][j] * dinv[i] * dinv[j]  (graph-major out)
// ============================================================================
__global__ __launch_bounds__(256) void scale_adj(const float* __restrict__ g,
                                                 const float* __restrict__ dinv,
                                                 __hip_bfloat16* __restrict__ out)
{
  const long long t = (long long)blockIdx.x * 256 + threadIdx.x; // quad index
  const long long e = t * 4;
  const int m = (int)(e >> 20);          // b*2+graph (input order)
  const int i = (int)((e >> 10) & 1023);
  const int j = (int)(e & 1023);
  const float4 v  = *(const float4*)(g + e);
  const float  di = dinv[m * 1024 + i];
  const float4 dj = *(const float4*)(dinv + m * 1024 + j);
  const int om = (m & 1) * 8 + (m >> 1); // z = graph*8 + b
  union { __hip_bfloat16 h[4]; unsigned long long u; } r;
  r.h[0] = __float2bfloat16(v.x * di * dj.x);
  r.h[1] = __float2bfloat16(v.y * di * dj.y);
  r.h[2] = __float2bfloat16(v.z * di * dj.z);
  r.h[3] = __float2bfloat16(v.w * di * dj.w);
  *(unsigned long long*)(out + ((long long)om << 20) + (long long)i * 1024 + j) = r.u;
}

// ============================================================================
// transpose + convert to bf16: out[C,R] = in[R,C], batched via grid.z
// ============================================================================
template<typename TIN>
__global__ void transpose_conv(const TIN* __restrict__ in, __hip_bfloat16* __restrict__ out,
                               int R, int C, long long sIn, long long sOut)
{
  __shared__ __hip_bfloat16 tile[32][33];
  in  += (long long)blockIdx.z * sIn;
  out += (long long)blockIdx.z * sOut;
  const int c0 = blockIdx.x * 32, r0 = blockIdx.y * 32;
  const int tx = threadIdx.x, ty = threadIdx.y;
#pragma unroll
  for (int i = 0; i < 32; i += 8)
    tile[ty + i][tx] = __float2bfloat16((float)in[(long long)(r0 + ty + i) * C + c0 + tx]);
  __syncthreads();
#pragma unroll
  for (int i = 0; i < 32; i += 8)
    out[(long long)(c0 + ty + i) * R + r0 + tx] = tile[tx][ty + i];
}

// ============================================================================
// residual + LayerNorm for BOTH graphs: rows [0,16384), g = row>>13.
// y = LN(nodes + V + col_b) -> bf16 slice of Gcat[r, g*768 : +768].  V bf16.
// ============================================================================
__global__ __launch_bounds__(256) void ln_residual2(
    const float* __restrict__ nodes, const __hip_bfloat16* __restrict__ V,
    const float* __restrict__ colb0, const float* __restrict__ colb1,
    const float* __restrict__ lng0,  const float* __restrict__ lng1,
    const float* __restrict__ lnb0,  const float* __restrict__ lnb1,
    __hip_bfloat16* __restrict__ gcat)
{
  const long long row = blockIdx.x;          // 0..16383
  const int g = (int)(row >> 13);
  const long long rr = row & 8191;           // node row
  const float* __restrict__ colb = g ? colb1 : colb0;
  const float* __restrict__ lng  = g ? lng1  : lng0;
  const float* __restrict__ lnb  = g ? lnb1  : lnb0;
  const int t = threadIdx.x;
  const long long nbase = rr * 768;
  const long long vbase = row * 768;
  float x[3]; float s = 0.0f, ss = 0.0f;
#pragma unroll
  for (int i = 0; i < 3; i++) {
    const int c = t + i * 256;
    const float v = nodes[nbase + c] + __bfloat162float(V[vbase + c]) + colb[c];
    x[i] = v; s += v; ss += v * v;
  }
  __shared__ float red[8];
#pragma unroll
  for (int o = 32; o > 0; o >>= 1) { s += __shfl_down(s, o); ss += __shfl_down(ss, o); }
  const int wave = t >> 6, lane = t & 63;
  if (lane == 0) { red[wave] = s; red[4 + wave] = ss; }
  __syncthreads();
  if (t == 0) {
    red[0] = red[0] + red[1] + red[2] + red[3];
    red[4] = red[4] + red[5] + red[6] + red[7];
  }
  __syncthreads();
  const float mu  = red[0] * (1.0f / 768.0f);
  float var = red[4] * (1.0f / 768.0f) - mu * mu;
  var = fmaxf(var, 0.0f);
  const float rs = rsqrtf(var + 1e-12f);
#pragma unroll
  for (int i = 0; i < 3; i++) {
    const int c = t + i * 256;
    const float y = (x[i] - mu) * rs * lng[c] + lnb[c];
    gcat[rr * 1536 + g * 768 + c] = __float2bfloat16(y);
  }
}

// ============================================================================
// WeffT[n][k] (bf16, [768,1536]): folded gate weight
//   k<768 : (Wa+Wc+Wd)[k][n];  k>=768: (Wb+Wc-Wd)[k-768][n]
// ============================================================================
__global__ __launch_bounds__(256) void build_wefft(const float* __restrict__ gw,
                                                   __hip_bfloat16* __restrict__ wt)
{
  const int idx = blockIdx.x * 256 + threadIdx.x;  // 768*1536, exact
  const int n = idx / 1536, k = idx % 1536;
  float v;
  if (k < 768) v = gw[k * 768 + n] + gw[(1536 + k) * 768 + n] + gw[(2304 + k) * 768 + n];
  else {
    const int kk = k - 768;
    v = gw[(768 + kk) * 768 + n] + gw[(1536 + kk) * 768 + n] - gw[(2304 + kk) * 768 + n];
  }
  wt[idx] = __float2bfloat16(v);
}

// ============================================================================
// out = sigmoid(logits + gate_b) * g1 + (1-sigmoid) * g2  (g1,g2 = Gcat halves)
// ============================================================================
__global__ __launch_bounds__(256) void final_gate(
    const float* __restrict__ logits, const float* __restrict__ gb,
    const __hip_bfloat16* __restrict__ gcat, float* __restrict__ out)
{
  const unsigned int t = blockIdx.x * 256u + threadIdx.x;  // quad index, < 1572864
  const unsigned int row = t / 192u;          // 192 quads per row of 768
  const unsigned int col = (t % 192u) * 4u;
  const long long e = (long long)row * 768 + col;
  const float4 L = *(const float4*)(logits + e);
  const float4 B = *(const float4*)(gb + col);
  union { __hip_bfloat16 h[4]; unsigned long long u; } g1, g2;
  g1.u = *(const unsigned long long*)(gcat + (long long)row * 1536 + col);
  g2.u = *(const unsigned long long*)(gcat + (long long)row * 1536 + 768 + col);
  float4 o;
  {
    float a = __bfloat162float(g1.h[0]), b = __bfloat162float(g2.h[0]);
    float s = 1.0f / (1.0f + expf(-(L.x + B.x))); o.x = s * a + (1.0f - s) * b;
  }
  {
    float a = __bfloat162float(g1.h[1]), b = __bfloat162float(g2.h[1]);
    float s = 1.0f / (1.0f + expf(-(L.y + B.y))); o.y = s * a + (1.0f - s) * b;
  }
  {
    float a = __bfloat162float(g1.h[2]), b = __bfloat162float(g2.h[2]);
    float s = 1.0f / (1.0f + expf(-(L.z + B.z))); o.z = s * a + (1.0f - s) * b;
  }
  {
    float a = __bfloat162float(g1.h[3]), b = __bfloat162float(g2.h[3]);
    float s = 1.0f / (1.0f + expf(-(L.w + B.w))); o.w = s * a + (1.0f - s) * b;
  }
  *(float4*)(out + e) = o;
}

// ============================================================================
extern "C" void kernel_launch(void* const* d_in, const int* in_sizes, int n_in,
                              void* d_out, int out_size, void* d_ws, size_t ws_size,
                              hipStream_t stream)
{
  const float* nodes  = (const float*)d_in[0];
  const float* graphs = (const float*)d_in[1];
  const float* gcn_w1[2] = { (const float*)d_in[2], (const float*)d_in[4] };
  const float* gcn_w2[2] = { (const float*)d_in[3], (const float*)d_in[5] };
  const float* exp_w[2]  = { (const float*)d_in[6],  (const float*)d_in[10] };
  const float* exp_b[2]  = { (const float*)d_in[7],  (const float*)d_in[11] };
  const float* col_w[2]  = { (const float*)d_in[8],  (const float*)d_in[12] };
  const float* col_b[2]  = { (const float*)d_in[9],  (const float*)d_in[13] };
  const float* gate_w = (const float*)d_in[14];
  const float* gate_b = (const float*)d_in[15];
  const float* ln_g[2] = { (const float*)d_in[16], (const float*)d_in[18] };
  const float* ln_b[2] = { (const float*)d_in[17], (const float*)d_in[19] };
  float* out = (float*)d_out;

  // ---- workspace carve-up (~196.3 MiB peak; lifetime-aliased regions) ----
  char* w = (char*)d_ws;
  auto alloc = [&](size_t bytes) { char* p = w; w += (bytes + 255) & ~(size_t)255; return p; };
  float*          dinv   = (float*)alloc(16384ULL * 4);                     // 64 KiB
  // region A (32 MiB): adj2 [16][1024][1024] bf16 (steps 1-6); Gcat [8192][1536] bf16 (9-11)
  char*           regA   = alloc(16ULL * 1024 * 1024 * 2);
  __hip_bfloat16* adj2   = (__hip_bfloat16*)regA;
  __hip_bfloat16* Gcat   = (__hip_bfloat16*)regA;
  __hip_bfloat16* wefft  = (__hip_bfloat16*)alloc(768ULL * 1536 * 2);       // 2.25 MiB
  // region C (24 MiB): bufA2 = AX / T2t / V, [16][1024][768] bf16
  __hip_bfloat16* bufA2  = (__hip_bfloat16*)alloc(16ULL * 1024 * 768 * 2);
  // region D (24 MiB): Xt [8][768][1024] bf16 (first 12 MiB, steps 0-2);
  //                    bufB2 = T2 / G, [16][1024][768] bf16 (steps 4-7)
  char*           regD   = alloc(16ULL * 1024 * 768 * 2);
  __hip_bfloat16* Xt     = (__hip_bfloat16*)regD;
  __hip_bfloat16* bufB2  = (__hip_bfloat16*)regD;
  // region E (96 MiB): X12 = X1 / U, [2][8192][3072] bf16; logits [8192][768] f32 (10-11)
  char*           regE   = alloc(2ULL * 8192 * 3072 * 2);
  __hip_bfloat16* X12    = (__hip_bfloat16*)regE;
  float*          logits = (float*)regE;
  // regions F/G (9 MiB each): w1T2/expT2 and w2T2/colT2 (rebuilt mid-stream)
  __hip_bfloat16* wgt1   = (__hip_bfloat16*)alloc(2ULL * 3072 * 768 * 2);
  __hip_bfloat16* wgt2   = (__hip_bfloat16*)alloc(2ULL * 768 * 3072 * 2);

  const long long sW1 = 3072LL * 768;   // w1T / expT per-graph elems
  const long long sW2 = 768LL * 3072;   // w2T / colT per-graph elems
  const long long sNM = 1024LL * 768;   // per-(g,b) node matrix elems
  const long long sBig = 8192LL * 3072; // per-graph X1/U elems

  // ---- prep ----
  rowsum_dinv<<<4096, 256, 0, stream>>>(graphs, dinv);
  transpose_conv<float><<<dim3(24, 32, 8), dim3(32, 8), 0, stream>>>(
      nodes, Xt, 1024, 768, 1024LL * 768, 768LL * 1024);
  build_wefft<<<4608, 256, 0, stream>>>(gate_w, wefft);
  scale_adj<<<16384, 256, 0, stream>>>(graphs, dinv, adj2);
  for (int g = 0; g < 2; g++) {
    transpose_conv<float><<<dim3(96, 24, 1), dim3(32, 8), 0, stream>>>(
        gcn_w1[g], wgt1 + g * sW1, 768, 3072, 0, 0);
    transpose_conv<float><<<dim3(24, 96, 1), dim3(32, 8), 0, stream>>>(
        gcn_w2[g], wgt2 + g * sW2, 3072, 768, 0, 0);
  }

  // ---- batched pipeline (z = graph*8 + b for per-matrix, z = graph for per-graph) ----
  // AX = adj @ X            [1024,1024]@[1024,768] x16  -> bufA2
  gemm_bt<0, 1><<<dim3(8, 6, 16), 256, 0, stream>>>(
      adj2, 1LL << 20, Xt, 768LL * 1024, bufA2, sNM, nullptr, nullptr, 768, 1024, 7);
  // X1 = relu(AX @ W1)      [8192,768]@[768,3072] x2    -> X12
  gemm_bt<1, 1><<<dim3(64, 24, 2), 256, 0, stream>>>(
      bufA2, 8192LL * 768, wgt1, sW1, X12, sBig, nullptr, nullptr, 3072, 768, -1);
  // T2 = X1 @ W2            [8192,3072]@[3072,768] x2   -> bufB2 (Xt dead)
  gemm_bt<0, 1><<<dim3(64, 6, 2), 256, 0, stream>>>(
      X12, sBig, wgt2, sW2, bufB2, 8192LL * 768, nullptr, nullptr, 768, 3072, -1);
  // rebuild weight regions with exp/col transposes (w1T/w2T now dead)
  for (int g = 0; g < 2; g++) {
    transpose_conv<float><<<dim3(96, 24, 1), dim3(32, 8), 0, stream>>>(
        exp_w[g], wgt1 + g * sW1, 768, 3072, 0, 0);
    transpose_conv<float><<<dim3(24, 96, 1), dim3(32, 8), 0, stream>>>(
        col_w[g], wgt2 + g * sW2, 3072, 768, 0, 0);
  }
  // T2t = per-(g,b) transpose of T2 -> bufA2 (AX dead)
  transpose_conv<__hip_bfloat16><<<dim3(24, 32, 16), dim3(32, 8), 0, stream>>>(
      bufB2, bufA2, 1024, 768, 1024LL * 768, 768LL * 1024);
  // G = relu(adj @ T2)      [1024,1024]@[1024,768] x16  -> bufB2 (T2 dead)
  gemm_bt<1, 1><<<dim3(8, 6, 16), 256, 0, stream>>>(
      adj2, 1LL << 20, bufA2, 768LL * 1024, bufB2, sNM, nullptr, nullptr, 768, 1024, -1);
  // U = gelu(G @ expW + b)  [8192,768]@[768,3072] x2    -> X12 (X1 dead)
  gemm_bt<2, 1><<<dim3(64, 24, 2), 256, 0, stream>>>(
      bufB2, 8192LL * 768, wgt1, sW1, X12, sBig, exp_b[0], exp_b[1], 3072, 768, -1);
  // V = U @ colW            [8192,3072]@[3072,768] x2   -> bufA2 (T2t dead)
  gemm_bt<0, 1><<<dim3(64, 6, 2), 256, 0, stream>>>(
      X12, sBig, wgt2, sW2, bufA2, 8192LL * 768, nullptr, nullptr, 768, 3072, -1);
  // LN(nodes + V + col_b) both graphs -> Gcat (adj2 dead)
  ln_residual2<<<16384, 256, 0, stream>>>(
      nodes, bufA2, col_b[0], col_b[1], ln_g[0], ln_g[1], ln_b[0], ln_b[1], Gcat);
  // logits = Gcat @ WeffT^T [8192,1536]@[1536,768], fp32 -> region E (U dead)
  gemm_bt<0, 0><<<dim3(64, 6, 1), 256, 0, stream>>>(
      Gcat, 0, wefft, 0, logits, 0, nullptr, nullptr, 768, 1536, -1);
  final_gate<<<6144, 256, 0, stream>>>(logits, gate_b, Gcat, out);
}